// Round 9
// baseline (26985.953 us; speedup 1.0000x reference)
//
#include <hip/hip_runtime.h>
#include <math.h>

typedef __attribute__((ext_vector_type(8))) __bf16          bf16x8;
typedef __attribute__((ext_vector_type(8))) unsigned short  ushort8;
typedef __attribute__((ext_vector_type(4))) float           f32x4;
typedef __attribute__((ext_vector_type(4))) unsigned int    u32x4;

constexpr int Bb = 128, Hh = 1024, Tt = 384, BH = Bb * Hh;
constexpr int NWG = 128, BLK = 512;   // 4 layers x 32 col-groups, 8 waves/WG

// h/x tile image: [plane2][kcg16][row128][col64] ushort, swizzled:
//   byte = plane*262144 + kcg*16384 + row*128 + ((col*2) ^ ((row&7)<<4))
constexpr size_t SLOT_B  = 524288;                    // one (B=128,K=1024) split tile
constexpr size_t OFF_H   = 1024;
constexpr size_t OFF_P   = OFF_H + 8 * SLOT_B;        // (reserved)
constexpr size_t OFF_W   = OFF_P + 128ull * 65536;
constexpr size_t WBLK_B  = 24576;                     // per (m,cg,kcg): hi[96][64], lo[96][64]
constexpr size_t OFF_X   = OFF_W + 2048ull * WBLK_B;  // 4 mats x 32 cg x 16 kcg
constexpr size_t WS_FULL = OFF_X + 384ull * SLOT_B;

__device__ __forceinline__ float b2f(unsigned short h) {
    unsigned u = ((unsigned)h) << 16;
    return __builtin_bit_cast(float, u);
}
__device__ __forceinline__ void split_bf16(float x, unsigned short& hi, unsigned short& lo) {
    unsigned u  = __builtin_bit_cast(unsigned, x);
    unsigned uh = u & 0xFFFF0000u;
    hi = (unsigned short)(uh >> 16);
    float rem = x - __builtin_bit_cast(float, uh);     // exact
    unsigned ur = __builtin_bit_cast(unsigned, rem);
    ur += 0x7FFFu + ((ur >> 16) & 1u);                 // RNE
    lo = (unsigned short)(ur >> 16);
}
__device__ __forceinline__ void split8(const float* src, ushort8& h8, ushort8& l8) {
    const float4* p4 = (const float4*)src;
    float4 a = p4[0], b = p4[1];
    float v[8] = {a.x, a.y, a.z, a.w, b.x, b.y, b.z, b.w};
    #pragma unroll
    for (int m = 0; m < 8; ++m) { unsigned short h, l; split_bf16(v[m], h, l); h8[m] = h; l8[m] = l; }
}
// staging loads: manual vmcnt control (asm results, compiler inserts no waits for them)
__device__ __forceinline__ u32x4 ld16_coh(const void* p) {   // bypass L1+L2 (coherent point)
    u32x4 r;
    asm volatile("global_load_dwordx4 %0, %1, off sc0 sc1" : "=v"(r) : "v"(p) : "memory");
    return r;
}
__device__ __forceinline__ u32x4 ld16c(const void* p) {      // cached (immutable data)
    u32x4 r;
    asm volatile("global_load_dwordx4 %0, %1, off" : "=v"(r) : "v"(p) : "memory");
    return r;
}

// ---------------- prologue kernels (layouts unchanged from r7/r8) ----------------

__global__ void wsplit_kernel(const float* __restrict__ W0i, const float* __restrict__ W0h,
                              const float* __restrict__ W1i, const float* __restrict__ W1h,
                              char* __restrict__ wbuf) {
    int t = blockIdx.x * 256 + threadIdx.x;
    if (t >= 2048 * 96 * 8) return;
    int g8 = t & 7;
    int gc = (t >> 3) % 96;
    int rest = (t >> 3) / 96;                // (m*32+cg)*16 + kcg
    int kcg = rest & 15, cg = (rest >> 4) & 31, m = rest >> 9;
    const float* W = (m == 0) ? W0i : (m == 1) ? W0h : (m == 2) ? W1i : W1h;
    int ct = gc >> 4, jl = gc & 15;
    int jh = ct / 3, g = ct % 3;
    const float* src = W + (size_t)(g * 1024 + cg * 32 + jh * 16 + jl) * 1024 + kcg * 64 + g8 * 8;
    ushort8 h8, l8; split8(src, h8, l8);
    char* blk = wbuf + (size_t)rest * WBLK_B;
    int boff = gc * 128 + ((g8 * 16) ^ ((gc & 7) << 4));
    *(ushort8*)(blk + boff)         = h8;
    *(ushort8*)(blk + 12288 + boff) = l8;
}

__global__ void xsplit_kernel(const float* __restrict__ xin, char* __restrict__ xb) {
    int t = blockIdx.x * 256 + threadIdx.x;
    if (t >= 384 * 16 * 128 * 8) return;
    int c8 = t & 7, b = (t >> 3) & 127, kc = (t >> 10) & 15, tau = t >> 14;
    const float* src = xin + ((size_t)b * 384 + tau) * 1024 + kc * 64 + c8 * 8;
    ushort8 h8, l8; split8(src, h8, l8);
    int boff = b * 128 + ((c8 * 16) ^ ((b & 7) << 4));
    char* dst = xb + (size_t)tau * SLOT_B + (size_t)kc * 16384 + boff;
    *(ushort8*)dst            = h8;
    *(ushort8*)(dst + 262144) = l8;
}

__global__ void hinit_kernel(const float* __restrict__ h0, char* __restrict__ ws) {
    int t = blockIdx.x * 256 + threadIdx.x;
    if (t == 0) *(unsigned*)ws = 0;
    if (t >= 4 * 128 * 128) return;
    char* hs = ws + OFF_H;
    int g = t & 127, b = (t >> 7) & 127, si = t >> 14;   // si 0..3 -> slot 1,3,5,7
    ushort8 h8, l8;
    if (si < 2) {
        split8(h0 + (size_t)si * BH + (size_t)b * 1024 + g * 8, h8, l8);
    } else {
        #pragma unroll
        for (int m = 0; m < 8; ++m) { h8[m] = 0; l8[m] = 0; }
    }
    int kc = g >> 3;
    int boff = b * 128 + (((g & 7) * 16) ^ ((b & 7) << 4));
    char* dst = hs + (size_t)(si * 2 + 1) * SLOT_B + (size_t)kc * 16384 + boff;
    *(ushort8*)dst            = h8;
    *(ushort8*)(dst + 262144) = l8;
}

// ---------------- main persistent kernel ----------------

__device__ __forceinline__ void grid_barrier(unsigned* cnt, unsigned target) {
    __syncthreads();   // drains vmcnt(0): sc1 h-stores at coherent point
    if (threadIdx.x == 0) {
        __hip_atomic_fetch_add(cnt, 1u, __ATOMIC_RELEASE, __HIP_MEMORY_SCOPE_AGENT);
        while (__hip_atomic_load(cnt, __ATOMIC_RELAXED, __HIP_MEMORY_SCOPE_AGENT) < target)
            __builtin_amdgcn_s_sleep(1);
    }
    __syncthreads();
}

template<bool XS>
__global__ __launch_bounds__(BLK, 2) void gru_persistent(
    const float* __restrict__ xin,
    const float* __restrict__ bih0, const float* __restrict__ bhh0,
    const float* __restrict__ bih1, const float* __restrict__ bhh1,
    unsigned* __restrict__ cnt, char* __restrict__ ws)
{
    __shared__ char AsB[2][32768];   // 64 KiB: 2 bufs x {hi 16K, lo 16K} (swizzled rows)
    __shared__ char BsB[2][24576];   // 48 KiB: 2 bufs x {hi 12K, lo 12K}

    char*       hs = ws + OFF_H;
    const char* wb = ws + OFF_W;
    const char* xs = ws + OFF_X;

    const int bid = blockIdx.x, layer = bid >> 5, cg = bid & 31;
    const int jbase = cg * 32;
    const int tid = threadIdx.x, lane = tid & 63, wv = tid >> 6;   // 8 waves
    const int jh = wv >> 2;        // ct-group (owned 16 jcols)
    const int rg = wv & 3;         // row-group (owned 32 batch rows)

    const float* bih = (layer & 1) ? bih1 : bih0;
    const float* bhh = (layer & 1) ? bhh1 : bhh0;
    const int jl = lane & 15;
    const int jcol = jbase + jh * 16 + jl;
    const int kcj = jcol >> 6, colj = jcol & 63;
    const float b_ir = bih[jcol],          b_hr = bhh[jcol];
    const float b_iz = bih[Hh + jcol],     b_hz = bhh[Hh + jcol];
    const float b_in = bih[2 * Hh + jcol], b_hn = bhh[2 * Hh + jcol];

    auto hoff = [&](int b, int plane) -> size_t {
        return (size_t)plane * 262144 + (size_t)kcj * 16384
             + (size_t)(b * 128 + (((colj * 2) ^ ((b & 7) << 4))));
    };

    float hreg[8];          // h_old: [rb 0..1][q 0..3], rows b = rg*32 + rb*16 + (lane>>4)*4 + q
    const bool fb0 = (!XS) && (layer == 0);

    unsigned target = NWG;
    for (int s = 0; s < Tt + 3; ++s, target += NWG) {
        const int tau = s - layer;
        if (tau >= 0 && tau < Tt) {
            const char* Axb = (layer == 0) ? (xs + (size_t)tau * SLOT_B)
                                           : (hs + (size_t)(((layer - 1) * 2) + (tau & 1)) * SLOT_B);
            const char* Ahb = hs + (size_t)((layer * 2) + ((tau - 1) & 1)) * SLOT_B;
            char*       Hd  = hs + (size_t)((layer * 2) + (tau & 1)) * SLOT_B;

            if (tau == 0) {
                if (layer < 2) {
                    #pragma unroll
                    for (int rb = 0; rb < 2; ++rb)
                        #pragma unroll
                        for (int q = 0; q < 4; ++q) {
                            int b = rg * 32 + rb * 16 + (lane >> 4) * 4 + q;
                            unsigned short hi = __hip_atomic_load(
                                (const unsigned short*)(Ahb + hoff(b, 0)),
                                __ATOMIC_RELAXED, __HIP_MEMORY_SCOPE_AGENT);
                            unsigned short lo = __hip_atomic_load(
                                (const unsigned short*)(Ahb + hoff(b, 1)),
                                __ATOMIC_RELAXED, __HIP_MEMORY_SCOPE_AGENT);
                            hreg[rb * 4 + q] = b2f(hi) + b2f(lo);
                        }
                    asm volatile("s_waitcnt vmcnt(0)" ::: "memory");  // clean vmcnt ledger
                } else {
                    #pragma unroll
                    for (int i = 0; i < 8; ++i) hreg[i] = 0.f;
                }
            }

            // ---------- staging helpers (chunk ch in [0,32): ch<16 = X-part, else H-part) ----------
            auto issueA = [&](int ch, u32x4* ra) {       // 4 asm loads, 16B/thread each
                const int kcg = ch & 15;
                const bool isX = ch < 16;
                const char* Ab = isX ? Axb : Ahb;
                const bool coh = !(isX && layer == 0);   // dynamic h tiles: coherent
                #pragma unroll
                for (int i = 0; i < 4; ++i) {
                    int o = i * 8192 + tid * 16;
                    const char* g = Ab + (size_t)(i >> 1) * 262144 + (size_t)kcg * 16384
                                  + (o & 16383);
                    ra[i] = coh ? ld16_coh(g) : ld16c(g);
                }
            };
            auto issueB = [&](int ch, u32x4* rb) {       // 3 asm loads (weights, cached)
                const int kcg = ch & 15;
                const int m = (layer & 1) * 2 + (ch < 16 ? 0 : 1);
                const char* Wb = wb + (size_t)(((m * 32 + cg) << 4) + kcg) * WBLK_B;
                #pragma unroll
                for (int i = 0; i < 3; ++i) rb[i] = ld16c(Wb + i * 8192 + tid * 16);
            };
            auto writeC = [&](int ch, const u32x4* ra, const u32x4* rb) {
                char* A = AsB[ch & 1]; char* B = BsB[ch & 1];
                #pragma unroll
                for (int i = 0; i < 4; ++i) *(u32x4*)(A + i * 8192 + tid * 16) = ra[i];
                #pragma unroll
                for (int i = 0; i < 3; ++i) *(u32x4*)(B + i * 8192 + tid * 16) = rb[i];
            };
            auto splitX = [&](int ch) {                  // fb0: on-the-fly layer-0 X -> LDS
                char* A = AsB[ch & 1];
                const int kcg = ch & 15;
                #pragma unroll
                for (int i2 = 0; i2 < 2; ++i2) {
                    int o = i2 * 8192 + tid * 16;
                    int row = o >> 7, sb_ = o & 127;
                    int cb = sb_ ^ ((row & 7) << 4);
                    const float* src = xin + ((size_t)row * 384 + tau) * 1024 + kcg * 64 + (cb >> 4) * 8;
                    ushort8 h8, l8; split8(src, h8, l8);
                    *(ushort8*)(A + o)         = h8;
                    *(ushort8*)(A + 16384 + o) = l8;
                }
            };
            auto compute = [&](int ch, f32x4 (&acc)[2][3]) {
                const char* A = AsB[ch & 1]; const char* B = BsB[ch & 1];
                __builtin_amdgcn_s_setprio(1);
                #pragma unroll
                for (int ks = 0; ks < 2; ++ks) {
                    const int kb = ks * 64 + (lane >> 4) * 16;
                    bf16x8 Bh[3], Bl[3];
                    #pragma unroll
                    for (int g = 0; g < 3; ++g) {
                        int brow = (jh * 3 + g) * 16 + (lane & 15);
                        int offB = brow * 128 + (kb ^ ((brow & 7) << 4));
                        Bh[g] = __builtin_bit_cast(bf16x8, *(const ushort8*)(B + offB));
                        Bl[g] = __builtin_bit_cast(bf16x8, *(const ushort8*)(B + 12288 + offB));
                    }
                    #pragma unroll
                    for (int rb = 0; rb < 2; ++rb) {
                        int arow = (rg * 2 + rb) * 16 + (lane & 15);
                        int offA = arow * 128 + (kb ^ ((arow & 7) << 4));
                        bf16x8 Ah = __builtin_bit_cast(bf16x8, *(const ushort8*)(A + offA));
                        bf16x8 Al = __builtin_bit_cast(bf16x8, *(const ushort8*)(A + 16384 + offA));
                        #pragma unroll
                        for (int g = 0; g < 3; ++g) {
                            f32x4 c = acc[rb][g];
                            c = __builtin_amdgcn_mfma_f32_16x16x32_bf16(Ah, Bh[g], c, 0, 0, 0);
                            c = __builtin_amdgcn_mfma_f32_16x16x32_bf16(Al, Bh[g], c, 0, 0, 0);
                            c = __builtin_amdgcn_mfma_f32_16x16x32_bf16(Ah, Bl[g], c, 0, 0, 0);
                            acc[rb][g] = c;
                        }
                    }
                }
                __builtin_amdgcn_s_setprio(0);
            };

            f32x4 accX[2][3], accH[2][3];
            const f32x4 zv = {0.f, 0.f, 0.f, 0.f};
            #pragma unroll
            for (int rb = 0; rb < 2; ++rb)
                #pragma unroll
                for (int g = 0; g < 3; ++g) { accX[rb][g] = zv; accH[rb][g] = zv; }

            if (!fb0) {
                // ---- 4-slot register ring, 2-buffer LDS, counted vmcnt (7 loads/chunk) ----
                u32x4 sa[4][4]; u32x4 sb[4][3];
                #pragma unroll
                for (int c0 = 0; c0 < 4; ++c0) { issueA(c0, sa[c0]); issueB(c0, sb[c0]); }
                asm volatile("s_waitcnt vmcnt(21)" ::: "memory");   // chunk 0 landed
                writeC(0, sa[0], sb[0]);
                asm volatile("s_waitcnt lgkmcnt(0)" ::: "memory");
                __builtin_amdgcn_s_barrier();
                __builtin_amdgcn_sched_barrier(0);
                #pragma unroll
                for (int ch = 0; ch < 32; ++ch) {
                    if (ch + 4 < 32) { issueA(ch + 4, sa[ch & 3]); issueB(ch + 4, sb[ch & 3]); }
                    if (ch < 31) {
                        if (ch <= 27)      asm volatile("s_waitcnt vmcnt(21)" ::: "memory");
                        else if (ch == 28) asm volatile("s_waitcnt vmcnt(14)" ::: "memory");
                        else if (ch == 29) asm volatile("s_waitcnt vmcnt(7)"  ::: "memory");
                        else               asm volatile("s_waitcnt vmcnt(0)"  ::: "memory");
                        writeC(ch + 1, sa[(ch + 1) & 3], sb[(ch + 1) & 3]);
                    }
                    if (ch < 16) compute(ch, accX); else compute(ch, accH);
                    asm volatile("s_waitcnt lgkmcnt(0)" ::: "memory");
                    __builtin_amdgcn_s_barrier();
                    __builtin_amdgcn_sched_barrier(0);
                }
            } else {
                // ---- fb0 fallback: distance-1, vmcnt(0) per iter ----
                u32x4 fa[4]; u32x4 fbv[3];
                splitX(0); issueB(0, fbv);
                asm volatile("s_waitcnt vmcnt(0)" ::: "memory");
                { char* B = BsB[0];
                  #pragma unroll
                  for (int i = 0; i < 3; ++i) *(u32x4*)(B + i * 8192 + tid * 16) = fbv[i]; }
                asm volatile("s_waitcnt lgkmcnt(0)" ::: "memory");
                __builtin_amdgcn_s_barrier();
                __builtin_amdgcn_sched_barrier(0);
                #pragma unroll
                for (int ch = 0; ch < 32; ++ch) {
                    const bool hn = (ch + 1) < 32;
                    if (hn) {
                        issueB(ch + 1, fbv);
                        if (ch + 1 < 16) splitX(ch + 1);
                        else             issueA(ch + 1, fa);
                        asm volatile("s_waitcnt vmcnt(0)" ::: "memory");
                        char* A = AsB[(ch + 1) & 1]; char* B = BsB[(ch + 1) & 1];
                        if (ch + 1 >= 16) {
                            #pragma unroll
                            for (int i = 0; i < 4; ++i) *(u32x4*)(A + i * 8192 + tid * 16) = fa[i];
                        }
                        #pragma unroll
                        for (int i = 0; i < 3; ++i) *(u32x4*)(B + i * 8192 + tid * 16) = fbv[i];
                    }
                    if (ch < 16) compute(ch, accX); else compute(ch, accH);
                    asm volatile("s_waitcnt lgkmcnt(0)" ::: "memory");
                    __builtin_amdgcn_s_barrier();
                    __builtin_amdgcn_sched_barrier(0);
                }
            }

            // ---- gates + state update; h as sc1 atomic bf16 pairs ----
            #pragma unroll
            for (int rb = 0; rb < 2; ++rb)
                #pragma unroll
                for (int q = 0; q < 4; ++q) {
                    const int b = rg * 32 + rb * 16 + (lane >> 4) * 4 + q;
                    float rp = accX[rb][0][q] + accH[rb][0][q] + b_ir + b_hr;
                    float zp = accX[rb][1][q] + accH[rb][1][q] + b_iz + b_hz;
                    float xn = accX[rb][2][q] + b_in;
                    float hn = accH[rb][2][q] + b_hn;
                    float r  = 1.0f / (1.0f + expf(-rp));
                    float z  = 1.0f / (1.0f + expf(-zp));
                    float n  = tanhf(xn + r * hn);
                    float h  = (1.0f - z) * n + z * hreg[rb * 4 + q];
                    hreg[rb * 4 + q] = h;
                    unsigned short hi, lo; split_bf16(h, hi, lo);
                    __hip_atomic_store((unsigned short*)(Hd + hoff(b, 0)), hi,
                                       __ATOMIC_RELAXED, __HIP_MEMORY_SCOPE_AGENT);
                    __hip_atomic_store((unsigned short*)(Hd + hoff(b, 1)), lo,
                                       __ATOMIC_RELAXED, __HIP_MEMORY_SCOPE_AGENT);
                }
        }
        grid_barrier(cnt, target);
    }
}

__global__ void pred_kernel(const char* __restrict__ hs,
                            const float* __restrict__ linW,
                            const float* __restrict__ linb,
                            float* __restrict__ out) {
    const int b = blockIdx.x, l = threadIdx.x;   // 64 threads
    const char* slot = hs + 7 * SLOT_B;
    float s = 0.f;
    for (int u = l; u < Hh; u += 64) {
        int kc = u >> 6, col = u & 63;
        size_t o = (size_t)kc * 16384 + (size_t)(b * 128 + (((col * 2) ^ ((b & 7) << 4))));
        float hv = b2f(*(const unsigned short*)(slot + o))
                 + b2f(*(const unsigned short*)(slot + 262144 + o));
        s += hv * linW[u];
    }
    #pragma unroll
    for (int off = 32; off > 0; off >>= 1) s += __shfl_down(s, off);
    if (l == 0) out[b] = s + linb[0];
}

extern "C" void kernel_launch(void* const* d_in, const int* in_sizes, int n_in,
                              void* d_out, int out_size, void* d_ws, size_t ws_size,
                              hipStream_t stream) {
    const float* rand_in = (const float*)d_in[1];
    const float* h0      = (const float*)d_in[2];
    const float* Wih0    = (const float*)d_in[7];
    const float* Whh0    = (const float*)d_in[8];
    const float* bih0    = (const float*)d_in[9];
    const float* bhh0    = (const float*)d_in[10];
    const float* Wih1    = (const float*)d_in[11];
    const float* Whh1    = (const float*)d_in[12];
    const float* bih1    = (const float*)d_in[13];
    const float* bhh1    = (const float*)d_in[14];
    const float* linW    = (const float*)d_in[15];
    const float* linb    = (const float*)d_in[16];
    float* out = (float*)d_out;

    char*     ws  = (char*)d_ws;
    unsigned* cnt = (unsigned*)d_ws;
    char*     hsl = ws + OFF_H;

    const bool xsl = (ws_size >= WS_FULL);

    wsplit_kernel<<<6144, 256, 0, stream>>>(Wih0, Whh0, Wih1, Whh1, ws + OFF_W);
    hinit_kernel<<<256, 256, 0, stream>>>(h0, ws);
    if (xsl) {
        xsplit_kernel<<<24576, 256, 0, stream>>>(rand_in, ws + OFF_X);
        gru_persistent<true><<<NWG, BLK, 0, stream>>>(rand_in, bih0, bhh0, bih1, bhh1, cnt, ws);
    } else {
        gru_persistent<false><<<NWG, BLK, 0, stream>>>(rand_in, bih0, bhh0, bih1, bhh1, cnt, ws);
    }
    pred_kernel<<<Bb, 64, 0, stream>>>(hsl, linW, linb, out);
}

// Round 10
// 14611.317 us; speedup vs baseline: 1.8469x; 1.8469x over previous
//
#include <hip/hip_runtime.h>
#include <math.h>

typedef __attribute__((ext_vector_type(8))) __bf16          bf16x8;
typedef __attribute__((ext_vector_type(8))) unsigned short  ushort8;
typedef __attribute__((ext_vector_type(4))) float           f32x4;
typedef __attribute__((ext_vector_type(4))) unsigned int    u32x4;

constexpr int Bb = 128, Hh = 1024, Tt = 384, BH = Bb * Hh;
constexpr int NWG = 256, BLK = 256;   // 4 layers x 64 jwg (16 jcols), 4 waves/WG

// Fragment-linear X/H slot: 512 KB = 16 kcg x 32 blocks x 1 KB.
// block BI = kcg*32 + rg*8 + rb*4 + pl*2 + ks ; within block: lane*16 (lane = kg*16+row16)
// holds A[row = rg*32+rb*16+row16][k = kcg*64+ks*32+kg*8 .. +8] plane pl (8 bf16).
constexpr size_t SLOT_B  = 524288;
constexpr size_t OFF_H   = 1024;
constexpr size_t OFF_W   = OFF_H + 8 * SLOT_B;
constexpr size_t WBLK_B  = 12288;                     // per (m,jwg,kcg): 12 blocks x 1 KB
constexpr size_t OFF_X   = OFF_W + 4096ull * WBLK_B;  // 4 mats x 64 jwg x 16 kcg
constexpr size_t WS_FULL = OFF_X + 384ull * SLOT_B;

__device__ __forceinline__ float b2f(unsigned short h) {
    unsigned u = ((unsigned)h) << 16;
    return __builtin_bit_cast(float, u);
}
__device__ __forceinline__ void split_bf16(float x, unsigned short& hi, unsigned short& lo) {
    unsigned u  = __builtin_bit_cast(unsigned, x);
    unsigned uh = u & 0xFFFF0000u;
    hi = (unsigned short)(uh >> 16);
    float rem = x - __builtin_bit_cast(float, uh);     // exact
    unsigned ur = __builtin_bit_cast(unsigned, rem);
    ur += 0x7FFFu + ((ur >> 16) & 1u);                 // RNE
    lo = (unsigned short)(ur >> 16);
}
__device__ __forceinline__ void split8(const float* src, ushort8& h8, ushort8& l8) {
    const float4* p4 = (const float4*)src;
    float4 a = p4[0], b = p4[1];
    float v[8] = {a.x, a.y, a.z, a.w, b.x, b.y, b.z, b.w};
    #pragma unroll
    for (int m = 0; m < 8; ++m) { unsigned short h, l; split_bf16(v[m], h, l); h8[m] = h; l8[m] = l; }
}
__device__ __forceinline__ void async16(const void* g, void* l) {
    __builtin_amdgcn_global_load_lds(
        (const __attribute__((address_space(1))) unsigned int*)g,
        (__attribute__((address_space(3))) unsigned int*)l, 16, 0, 0);
}

// ---------------- prologue kernels (fragment-linear emit) ----------------

__global__ void wsplit_kernel(const float* __restrict__ W0i, const float* __restrict__ W0h,
                              const float* __restrict__ W1i, const float* __restrict__ W1h,
                              char* __restrict__ wbuf) {
    int t = blockIdx.x * 256 + threadIdx.x;
    if (t >= 4 * 64 * 16 * 48 * 8) return;
    int g8 = t & 7;
    int r  = (t >> 3) % 48;                  // ct*16 + jl
    int rest = (t >> 3) / 48;                // ((m*64+jwg)*16+kcg)
    int kcg = rest & 15, jwg = (rest >> 4) & 63, m = rest >> 10;
    const float* W = (m == 0) ? W0i : (m == 1) ? W0h : (m == 2) ? W1i : W1h;
    int ct = r >> 4, jl = r & 15;
    const float* src = W + (size_t)((ct << 10) + jwg * 16 + jl) * 1024 + kcg * 64 + g8 * 8;
    ushort8 h8, l8; split8(src, h8, l8);
    int ks = (g8 >> 2) & 1, kg = g8 & 3, lane = kg * 16 + jl;
    char* blk = wbuf + (size_t)rest * WBLK_B;
    int off0 = (ct * 4 + ks) * 1024 + lane * 16;   // pl=0 ; pl=1 at +2048
    *(ushort8*)(blk + off0)        = h8;
    *(ushort8*)(blk + off0 + 2048) = l8;
}

__global__ void xsplit_kernel(const float* __restrict__ xin, char* __restrict__ xb) {
    int t = blockIdx.x * 256 + threadIdx.x;
    if (t >= 384 * 128 * 128) return;
    int g8 = t & 127, b = (t >> 7) & 127, tau = t >> 14;
    const float* src = xin + ((size_t)b * 384 + tau) * 1024 + g8 * 8;
    ushort8 h8, l8; split8(src, h8, l8);
    int kcg = g8 >> 3, gin = g8 & 7;
    int ks = (gin >> 2) & 1, kg = gin & 3;
    int lane = kg * 16 + (b & 15);
    int BI0 = kcg * 32 + (b >> 5) * 8 + ((b >> 4) & 1) * 4 + ks;
    char* dst = xb + (size_t)tau * SLOT_B + (size_t)BI0 * 1024 + lane * 16;
    *(ushort8*)dst          = h8;
    *(ushort8*)(dst + 2048) = l8;
}

__global__ void hinit_kernel(const float* __restrict__ h0, char* __restrict__ ws) {
    int t = blockIdx.x * 256 + threadIdx.x;
    if (t == 0) *(unsigned*)ws = 0;
    if (t >= 4 * 128 * 128) return;
    char* hs = ws + OFF_H;
    int g8 = t & 127, b = (t >> 7) & 127, si = t >> 14;   // si 0..3 -> slot 1,3,5,7
    ushort8 h8, l8;
    if (si < 2) {
        split8(h0 + (size_t)si * BH + (size_t)b * 1024 + g8 * 8, h8, l8);
    } else {
        #pragma unroll
        for (int m = 0; m < 8; ++m) { h8[m] = 0; l8[m] = 0; }
    }
    int kcg = g8 >> 3, gin = g8 & 7;
    int ks = (gin >> 2) & 1, kg = gin & 3;
    int lane = kg * 16 + (b & 15);
    int BI0 = kcg * 32 + (b >> 5) * 8 + ((b >> 4) & 1) * 4 + ks;
    char* dst = hs + (size_t)(si * 2 + 1) * SLOT_B + (size_t)BI0 * 1024 + lane * 16;
    *(ushort8*)dst          = h8;
    *(ushort8*)(dst + 2048) = l8;
}

// ---------------- main persistent kernel ----------------

__device__ __forceinline__ void grid_barrier(unsigned* cnt, unsigned target) {
    __syncthreads();   // drains vmcnt(0): sc1 h-stores at coherent point
    if (threadIdx.x == 0) {
        __hip_atomic_fetch_add(cnt, 1u, __ATOMIC_RELEASE, __HIP_MEMORY_SCOPE_AGENT);
        while (__hip_atomic_load(cnt, __ATOMIC_RELAXED, __HIP_MEMORY_SCOPE_AGENT) < target)
            __builtin_amdgcn_s_sleep(1);
    }
    __syncthreads();
}

#define WAITVM(N) asm volatile("s_waitcnt vmcnt(" #N ")" ::: "memory")

// one pipeline iteration: wait chunk CH landed -> barrier -> issue CH+3 -> compute CH
#define GITER(CH, SLOT, ACC, WN, DOISS)                                  \
    WAITVM(WN);                                                          \
    asm volatile("" ::: "memory");                                       \
    __builtin_amdgcn_s_barrier();                                        \
    __builtin_amdgcn_sched_barrier(0);                                   \
    if (DOISS) { issueA((CH) + 3, ar[((SLOT) + 3) & 3]);                 \
                 issueB((CH) + 3, ((SLOT) + 3) & 3); }                   \
    computeC(ar[SLOT], (SLOT), ACC);

template<bool XS>
__global__ __launch_bounds__(BLK, 2) void gru_persistent(
    const float* __restrict__ xin,
    const float* __restrict__ bih0, const float* __restrict__ bhh0,
    const float* __restrict__ bih1, const float* __restrict__ bhh1,
    unsigned* __restrict__ cnt, char* __restrict__ ws)
{
    __shared__ char Bs[4][12288];    // 48 KiB: B 4-deep, fragment-linear

    char*       hs = ws + OFF_H;
    const char* wb = ws + OFF_W;
    const char* xs = ws + OFF_X;

    const int bid = blockIdx.x, layer = bid >> 6, jwg = bid & 63, jbase = jwg * 16;
    const int tid = threadIdx.x, lane = tid & 63, rg = tid >> 6;   // 4 waves = 4 row groups

    const float* bih = (layer & 1) ? bih1 : bih0;
    const float* bhh = (layer & 1) ? bhh1 : bhh0;
    const int jl = lane & 15;
    const int jcol = jbase + jl;
    const float b_ir = bih[jcol],          b_hr = bhh[jcol];
    const float b_iz = bih[Hh + jcol],     b_hz = bhh[Hh + jcol];
    const float b_in = bih[2 * Hh + jcol], b_hn = bhh[2 * Hh + jcol];

    // h-store/load offsets for owned (b, jcol): b = rg*32 + rb*16 + (lane>>4)*4 + q
    const int kcg_j = jcol >> 6, ks_j = (jcol >> 5) & 1, kg_j = (jcol >> 3) & 3, e_j = jcol & 7;
    const int baseBI = kcg_j * 32 + rg * 8 + ks_j;
    auto hoff = [&](int rb, int pl, int q) -> size_t {
        return (size_t)(baseBI + rb * 4 + pl * 2) * 1024
             + (size_t)(kg_j * 16 + (lane >> 4) * 4 + q) * 16 + e_j * 2;
    };

    float hreg[8];          // h_old: [rb][q]
    const bool fb0 = (!XS) && (layer == 0);

    unsigned target = NWG;
    for (int s = 0; s < Tt + 3; ++s, target += NWG) {
        const int tau = s - layer;
        if (tau >= 0 && tau < Tt) {
            const char* Axb = (layer == 0) ? (xs + (size_t)tau * SLOT_B)
                                           : (hs + (size_t)(((layer - 1) * 2) + (tau & 1)) * SLOT_B);
            const char* Ahb = hs + (size_t)((layer * 2) + ((tau - 1) & 1)) * SLOT_B;
            char*       Hd  = hs + (size_t)((layer * 2) + (tau & 1)) * SLOT_B;

            if (tau == 0) {
                if (layer < 2) {
                    #pragma unroll
                    for (int rb = 0; rb < 2; ++rb)
                        #pragma unroll
                        for (int q = 0; q < 4; ++q) {
                            unsigned short hi = __hip_atomic_load(
                                (const unsigned short*)(Ahb + hoff(rb, 0, q)),
                                __ATOMIC_RELAXED, __HIP_MEMORY_SCOPE_AGENT);
                            unsigned short lo = __hip_atomic_load(
                                (const unsigned short*)(Ahb + hoff(rb, 1, q)),
                                __ATOMIC_RELAXED, __HIP_MEMORY_SCOPE_AGENT);
                            hreg[rb * 4 + q] = b2f(hi) + b2f(lo);
                        }
                    asm volatile("s_waitcnt vmcnt(0)" ::: "memory");  // clean ledger
                } else {
                    #pragma unroll
                    for (int i = 0; i < 8; ++i) hreg[i] = 0.f;
                }
            }

            // ---- staging: chunk ch in [0,32): ch<16 = X-stream, else H-stream ----
            auto issueA = [&](int ch, u32x4* fr) {       // 8 asm loads -> VGPR frags
                const char* base = ((ch < 16) ? Axb : Ahb)
                                 + ((size_t)(ch & 15) << 15) + (rg << 13) + (lane << 4);
                #pragma unroll
                for (int rb = 0; rb < 2; ++rb) {
                    const char* p = base + (rb << 12);
                    asm volatile("global_load_dwordx4 %0, %1, off sc0 sc1"             : "=v"(fr[rb*4+0]) : "v"(p));
                    asm volatile("global_load_dwordx4 %0, %1, off offset:1024 sc0 sc1" : "=v"(fr[rb*4+1]) : "v"(p));
                    asm volatile("global_load_dwordx4 %0, %1, off offset:2048 sc0 sc1" : "=v"(fr[rb*4+2]) : "v"(p));
                    asm volatile("global_load_dwordx4 %0, %1, off offset:3072 sc0 sc1" : "=v"(fr[rb*4+3]) : "v"(p));
                }
            };
            auto issueB = [&](int ch, int buf) {         // 3 DMA -> LDS (cached)
                const int m = (layer & 1) * 2 + (ch < 16 ? 0 : 1);
                const char* Wb = wb + (size_t)(((m * 64 + jwg) << 4) + (ch & 15)) * WBLK_B;
                char* L = &Bs[buf][0];
                #pragma unroll
                for (int i = 0; i < 3; ++i) {
                    int seg = rg + i * 4;
                    async16(Wb + seg * 1024 + lane * 16, L + seg * 1024);
                }
            };
            auto fragX = [&](int ch, u32x4* fr) {        // fb0: on-the-fly layer-0 X frags
                const int kcg = ch & 15;
                #pragma unroll
                for (int rb = 0; rb < 2; ++rb)
                    #pragma unroll
                    for (int ks = 0; ks < 2; ++ks) {
                        int row = rg * 32 + rb * 16 + (lane & 15);
                        int k0  = kcg * 64 + ks * 32 + (lane >> 4) * 8;
                        ushort8 h8, l8;
                        split8(xin + ((size_t)row * 384 + tau) * 1024 + k0, h8, l8);
                        fr[rb * 4 + ks]     = __builtin_bit_cast(u32x4, h8);
                        fr[rb * 4 + 2 + ks] = __builtin_bit_cast(u32x4, l8);
                    }
            };
            auto computeC = [&](u32x4* fr, int buf, f32x4 (&acc)[2][3]) {
                const char* B = &Bs[buf][0];
                __builtin_amdgcn_s_setprio(1);
                #pragma unroll
                for (int ks = 0; ks < 2; ++ks) {
                    bf16x8 Bh[3], Bl[3];
                    #pragma unroll
                    for (int ct = 0; ct < 3; ++ct) {
                        Bh[ct] = __builtin_bit_cast(bf16x8, *(const ushort8*)(B + (ct*4 + ks)*1024 + lane*16));
                        Bl[ct] = __builtin_bit_cast(bf16x8, *(const ushort8*)(B + (ct*4 + 2 + ks)*1024 + lane*16));
                    }
                    #pragma unroll
                    for (int rb = 0; rb < 2; ++rb) {
                        bf16x8 Ah = __builtin_bit_cast(bf16x8, fr[rb*4 + ks]);
                        bf16x8 Al = __builtin_bit_cast(bf16x8, fr[rb*4 + 2 + ks]);
                        #pragma unroll
                        for (int ct = 0; ct < 3; ++ct) {
                            f32x4 c = acc[rb][ct];
                            c = __builtin_amdgcn_mfma_f32_16x16x32_bf16(Ah, Bh[ct], c, 0, 0, 0);
                            c = __builtin_amdgcn_mfma_f32_16x16x32_bf16(Al, Bh[ct], c, 0, 0, 0);
                            c = __builtin_amdgcn_mfma_f32_16x16x32_bf16(Ah, Bl[ct], c, 0, 0, 0);
                            acc[rb][ct] = c;
                        }
                    }
                }
                __builtin_amdgcn_s_setprio(0);
            };

            f32x4 accX[2][3], accH[2][3];
            const f32x4 zv = {0.f, 0.f, 0.f, 0.f};
            #pragma unroll
            for (int rb = 0; rb < 2; ++rb)
                #pragma unroll
                for (int ct = 0; ct < 3; ++ct) { accX[rb][ct] = zv; accH[rb][ct] = zv; }

            u32x4 ar[4][8];   // A-fragment ring, static slots only

            if (!fb0) {
                // prologue: chunks 0,1,2 in flight (33 loads/wave)
                issueA(0, ar[0]); issueB(0, 0);
                issueA(1, ar[1]); issueB(1, 1);
                issueA(2, ar[2]); issueB(2, 2);
                for (int c4 = 0; c4 < 16; c4 += 4) {        // X chunks 0..15
                    GITER(c4 + 0, 0, accX, 22, true);
                    GITER(c4 + 1, 1, accX, 22, true);
                    GITER(c4 + 2, 2, accX, 22, true);
                    GITER(c4 + 3, 3, accX, 22, true);
                }
                for (int c4 = 16; c4 < 28; c4 += 4) {       // H chunks 16..27
                    GITER(c4 + 0, 0, accH, 22, true);
                    GITER(c4 + 1, 1, accH, 22, true);
                    GITER(c4 + 2, 2, accH, 22, true);
                    GITER(c4 + 3, 3, accH, 22, true);
                }
                GITER(28, 0, accH, 22, true);               // issues 31
                GITER(29, 1, accH, 22, false);
                GITER(30, 2, accH, 11, false);
                GITER(31, 3, accH, 0,  false);
            } else {
                // fallback: simple double-barrier loop, vmcnt(0) per iter
                for (int ch = 0; ch < 32; ++ch) {
                    if (ch < 16) fragX(ch, ar[0]); else issueA(ch, ar[0]);
                    issueB(ch, 0);
                    asm volatile("s_waitcnt vmcnt(0)" ::: "memory");
                    asm volatile("" ::: "memory");
                    __builtin_amdgcn_s_barrier();
                    __builtin_amdgcn_sched_barrier(0);
                    if (ch < 16) computeC(ar[0], 0, accX); else computeC(ar[0], 0, accH);
                    asm volatile("" ::: "memory");
                    __builtin_amdgcn_s_barrier();
                    asm volatile("" ::: "memory");
                }
            }

            // ---- gates + state update; h as sc1 atomic bf16 pairs ----
            #pragma unroll
            for (int rb = 0; rb < 2; ++rb)
                #pragma unroll
                for (int q = 0; q < 4; ++q) {
                    float rp = accX[rb][0][q] + accH[rb][0][q] + b_ir + b_hr;
                    float zp = accX[rb][1][q] + accH[rb][1][q] + b_iz + b_hz;
                    float xn = accX[rb][2][q] + b_in;
                    float hn = accH[rb][2][q] + b_hn;
                    float r  = 1.0f / (1.0f + expf(-rp));
                    float z  = 1.0f / (1.0f + expf(-zp));
                    float n  = tanhf(xn + r * hn);
                    float h  = (1.0f - z) * n + z * hreg[rb * 4 + q];
                    hreg[rb * 4 + q] = h;
                    unsigned short hi, lo; split_bf16(h, hi, lo);
                    __hip_atomic_store((unsigned short*)(Hd + hoff(rb, 0, q)), hi,
                                       __ATOMIC_RELAXED, __HIP_MEMORY_SCOPE_AGENT);
                    __hip_atomic_store((unsigned short*)(Hd + hoff(rb, 1, q)), lo,
                                       __ATOMIC_RELAXED, __HIP_MEMORY_SCOPE_AGENT);
                }
        }
        grid_barrier(cnt, target);
    }
}

__global__ void pred_kernel(const char* __restrict__ hs,
                            const float* __restrict__ linW,
                            const float* __restrict__ linb,
                            float* __restrict__ out) {
    const int b = blockIdx.x, l = threadIdx.x;   // 64 threads
    const char* slot = hs + 7 * SLOT_B;
    const int rpart = (b >> 5) * 8 + ((b >> 4) & 1) * 4;
    float s = 0.f;
    for (int u = l; u < Hh; u += 64) {
        int BI0 = (u >> 6) * 32 + rpart + ((u >> 5) & 1);
        size_t o = (size_t)BI0 * 1024 + (size_t)(((u >> 3) & 3) * 16 + (b & 15)) * 16 + (u & 7) * 2;
        float hv = b2f(*(const unsigned short*)(slot + o))
                 + b2f(*(const unsigned short*)(slot + o + 2048));
        s += hv * linW[u];
    }
    #pragma unroll
    for (int off = 32; off > 0; off >>= 1) s += __shfl_down(s, off);
    if (l == 0) out[b] = s + linb[0];
}

extern "C" void kernel_launch(void* const* d_in, const int* in_sizes, int n_in,
                              void* d_out, int out_size, void* d_ws, size_t ws_size,
                              hipStream_t stream) {
    const float* rand_in = (const float*)d_in[1];
    const float* h0      = (const float*)d_in[2];
    const float* Wih0    = (const float*)d_in[7];
    const float* Whh0    = (const float*)d_in[8];
    const float* bih0    = (const float*)d_in[9];
    const float* bhh0    = (const float*)d_in[10];
    const float* Wih1    = (const float*)d_in[11];
    const float* Whh1    = (const float*)d_in[12];
    const float* bih1    = (const float*)d_in[13];
    const float* bhh1    = (const float*)d_in[14];
    const float* linW    = (const float*)d_in[15];
    const float* linb    = (const float*)d_in[16];
    float* out = (float*)d_out;

    char*     ws  = (char*)d_ws;
    unsigned* cnt = (unsigned*)d_ws;
    char*     hsl = ws + OFF_H;

    const bool xsl = (ws_size >= WS_FULL);

    wsplit_kernel<<<6144, 256, 0, stream>>>(Wih0, Whh0, Wih1, Whh1, ws + OFF_W);
    hinit_kernel<<<256, 256, 0, stream>>>(h0, ws);
    if (xsl) {
        xsplit_kernel<<<24576, 256, 0, stream>>>(rand_in, ws + OFF_X);
        gru_persistent<true><<<NWG, BLK, 0, stream>>>(rand_in, bih0, bhh0, bih1, bhh1, cnt, ws);
    } else {
        gru_persistent<false><<<NWG, BLK, 0, stream>>>(rand_in, bih0, bhh0, bih1, bhh1, cnt, ws);
    }
    pred_kernel<<<Bb, 64, 0, stream>>>(hsl, linW, linb, out);
}